// Round 1
// baseline (568.069 us; speedup 1.0000x reference)
//
#include <hip/hip_runtime.h>

#define D 128
#define NPB 4   // nodes per block in agg kernel (4 waves of 64)

// ---- CSR build ----------------------------------------------------------

__global__ __launch_bounds__(256) void count_k(const int* __restrict__ dst,
                                               int* __restrict__ deg, int E) {
  int e = blockIdx.x * 256 + threadIdx.x;
  if (e < E) atomicAdd(&deg[dst[e]], 1);
}

__global__ __launch_bounds__(256) void norm_k(const int* __restrict__ deg,
                                              float* __restrict__ nrm,
                                              int* __restrict__ row_start,
                                              int N, int E) {
  int i = blockIdx.x * 256 + threadIdx.x;
  if (i < N) nrm[i] = rsqrtf((float)deg[i] + 1.0f);
  if (i == 0) row_start[N] = E;  // total edges == sum of deg
}

__global__ __launch_bounds__(256) void bsum_k(const int* __restrict__ deg,
                                              int* __restrict__ bsum, int N) {
  __shared__ int s[256];
  int t = threadIdx.x, i = blockIdx.x * 256 + t;
  s[t] = (i < N) ? deg[i] : 0;
  __syncthreads();
  for (int off = 128; off > 0; off >>= 1) {
    if (t < off) s[t] += s[t + off];
    __syncthreads();
  }
  if (t == 0) bsum[blockIdx.x] = s[0];
}

// single-block inclusive scan of the (<=512) block sums
__global__ __launch_bounds__(512) void bscan_k(int* bsum, int nb) {
  __shared__ int s[512];
  int t = threadIdx.x;
  s[t] = (t < nb) ? bsum[t] : 0;
  __syncthreads();
  for (int off = 1; off < 512; off <<= 1) {
    int v = (t >= off) ? s[t - off] : 0;
    __syncthreads();
    s[t] += v;
    __syncthreads();
  }
  if (t < nb) bsum[t] = s[t];
}

__global__ __launch_bounds__(256) void scanfin_k(const int* __restrict__ deg,
                                                 const int* __restrict__ bsum_incl,
                                                 int* __restrict__ row_start, int N) {
  __shared__ int s[256];
  int b = blockIdx.x, t = threadIdx.x, i = b * 256 + t;
  int v0 = (i < N) ? deg[i] : 0;
  s[t] = v0;
  __syncthreads();
  for (int off = 1; off < 256; off <<= 1) {
    int v = (t >= off) ? s[t - off] : 0;
    __syncthreads();
    s[t] += v;
    __syncthreads();
  }
  int base = (b > 0) ? bsum_incl[b - 1] : 0;
  if (i < N) row_start[i] = base + s[t] - v0;  // exclusive scan + block offset
}

__global__ __launch_bounds__(256) void fill_k(const int* __restrict__ src,
                                              const int* __restrict__ dst,
                                              const int* __restrict__ row_start,
                                              int* __restrict__ cursor,
                                              int* __restrict__ esrc, int E) {
  int e = blockIdx.x * 256 + threadIdx.x;
  if (e < E) {
    int d = dst[e];
    int p = atomicAdd(&cursor[d], 1);
    esrc[row_start[d] + p] = src[e];
  }
}

// ---- GEMM: H = X @ W, X:[N,128], W:[128,128] row-major ------------------
// Block computes 32 rows x 128 cols; 4x4 register tile per thread.
// LDS: W half-tile 64x128 (32KB) + X tile 32x128 (16KB) = 48KB.
__global__ __launch_bounds__(256) void gemm_k(const float* __restrict__ X,
                                              const float* __restrict__ W,
                                              float* __restrict__ H) {
  __shared__ float Ws[64 * D];
  __shared__ float Xs[32 * D];
  int tid = threadIdx.x;
  int row0 = blockIdx.x * 32;

  {  // stage X tile: 4096 floats = 1024 float4, coalesced, linear LDS
    const float4* X4 = (const float4*)(X + (size_t)row0 * D);
    float4* Xs4 = (float4*)Xs;
#pragma unroll
    for (int it = 0; it < 4; ++it) Xs4[it * 256 + tid] = X4[it * 256 + tid];
  }

  int cg = tid & 31, rg = tid >> 5;
  int c0 = cg * 4, r0 = rg * 4;
  float acc[4][4] = {};

  for (int kh = 0; kh < 2; ++kh) {
    __syncthreads();  // protect Ws overwrite (and X stage on first pass)
    {  // stage W rows [kh*64, kh*64+64): 8192 floats = 2048 float4
      const float4* W4 = (const float4*)(W + kh * 64 * D);
      float4* Ws4 = (float4*)Ws;
#pragma unroll
      for (int it = 0; it < 8; ++it) Ws4[it * 256 + tid] = W4[it * 256 + tid];
    }
    __syncthreads();

    for (int k = 0; k < 64; k += 4) {
      float xr[4][4], wr[4][4];
#pragma unroll
      for (int r = 0; r < 4; ++r) {
        float4 v = *(const float4*)&Xs[(r0 + r) * D + kh * 64 + k];
        xr[r][0] = v.x; xr[r][1] = v.y; xr[r][2] = v.z; xr[r][3] = v.w;
      }
#pragma unroll
      for (int i = 0; i < 4; ++i) {
        float4 v = *(const float4*)&Ws[(k + i) * D + c0];
        wr[i][0] = v.x; wr[i][1] = v.y; wr[i][2] = v.z; wr[i][3] = v.w;
      }
#pragma unroll
      for (int i = 0; i < 4; ++i)
#pragma unroll
        for (int r = 0; r < 4; ++r)
#pragma unroll
          for (int c = 0; c < 4; ++c)
            acc[r][c] += xr[r][i] * wr[i][c];
    }
  }

#pragma unroll
  for (int r = 0; r < 4; ++r) {
    float4 v;
    v.x = acc[r][0]; v.y = acc[r][1]; v.z = acc[r][2]; v.w = acc[r][3];
    *(float4*)&H[(size_t)(row0 + r0 + r) * D + c0] = v;
  }
}

// ---- Fused aggregate + self-loop + bias + ReLU --------------------------
// One wave per destination node; lane owns 2 dims (float2).
__global__ __launch_bounds__(256) void agg_k(const float* __restrict__ H,
                                             const float* __restrict__ nrm,
                                             const int* __restrict__ row_start,
                                             const int* __restrict__ esrc,
                                             const float* __restrict__ bias,
                                             float* __restrict__ out, int N) {
  int wave = threadIdx.x >> 6, lane = threadIdx.x & 63;
  int n = blockIdx.x * NPB + wave;
  if (n >= N) return;
  int d = lane * 2;
  int i = row_start[n], end = row_start[n + 1];
  float ax = 0.f, ay = 0.f;
  for (; i + 1 < end; i += 2) {  // 2-way unroll for independent load chains
    int sa = esrc[i], sb = esrc[i + 1];
    float na = nrm[sa], nb = nrm[sb];
    float2 ha = *(const float2*)&H[(size_t)sa * D + d];
    float2 hb = *(const float2*)&H[(size_t)sb * D + d];
    ax += ha.x * na; ay += ha.y * na;
    ax += hb.x * nb; ay += hb.y * nb;
  }
  if (i < end) {
    int sa = esrc[i];
    float na = nrm[sa];
    float2 ha = *(const float2*)&H[(size_t)sa * D + d];
    ax += ha.x * na; ay += ha.y * na;
  }
  float nn = nrm[n];
  float2 hn = *(const float2*)&H[(size_t)n * D + d];
  float2 bv = *(const float2*)&bias[d];
  float vx = ax * nn + hn.x * nn * nn + bv.x;
  float vy = ay * nn + hn.y * nn * nn + bv.y;
  float2 o;
  o.x = fmaxf(vx, 0.f);
  o.y = fmaxf(vy, 0.f);
  *(float2*)&out[(size_t)n * D + d] = o;
}

// ---- launch -------------------------------------------------------------

extern "C" void kernel_launch(void* const* d_in, const int* in_sizes, int n_in,
                              void* d_out, int out_size, void* d_ws, size_t ws_size,
                              hipStream_t stream) {
  const float* x  = (const float*)d_in[0];
  const int*   ei = (const int*)d_in[1];
  const float* W1 = (const float*)d_in[2];
  const float* b1 = (const float*)d_in[3];
  const float* W2 = (const float*)d_in[4];
  const float* b2 = (const float*)d_in[5];
  float* out = (float*)d_out;

  int N = in_sizes[0] / D;   // 100000
  int E = in_sizes[1] / 2;   // 1600000
  const int* srcp = ei;
  const int* dstp = ei + E;

  char* ws = (char*)d_ws;
  size_t off = 0;
  auto alloc = [&](size_t bytes) -> char* {
    char* p = ws + off;
    off = (off + bytes + 511) & ~(size_t)511;
    return p;
  };
  float* Hb        = (float*)alloc((size_t)N * D * 4);   // 51.2 MB
  float* O1        = (float*)alloc((size_t)N * D * 4);   // 51.2 MB
  float* normv     = (float*)alloc((size_t)N * 4);
  int*   deg       = (int*)alloc((size_t)N * 4);
  int*   row_start = (int*)alloc((size_t)(N + 1) * 4);
  int*   cursor    = (int*)alloc((size_t)N * 4);
  int*   esrc      = (int*)alloc((size_t)E * 4);         // 6.4 MB
  int*   bsum      = (int*)alloc(4096);

  int nbN = (N + 255) / 256;  // 391  (must be <= 512 for bscan_k)
  int nbE = (E + 255) / 256;  // 6250

  hipMemsetAsync(deg, 0, (size_t)N * 4, stream);
  hipMemsetAsync(cursor, 0, (size_t)N * 4, stream);

  count_k<<<nbE, 256, 0, stream>>>(dstp, deg, E);
  norm_k<<<nbN, 256, 0, stream>>>(deg, normv, row_start, N, E);
  bsum_k<<<nbN, 256, 0, stream>>>(deg, bsum, N);
  bscan_k<<<1, 512, 0, stream>>>(bsum, nbN);
  scanfin_k<<<nbN, 256, 0, stream>>>(deg, bsum, row_start, N);
  fill_k<<<nbE, 256, 0, stream>>>(srcp, dstp, row_start, cursor, esrc, E);

  // Layer 1
  gemm_k<<<N / 32, 256, 0, stream>>>(x, W1, Hb);
  agg_k<<<(N + NPB - 1) / NPB, 256, 0, stream>>>(Hb, normv, row_start, esrc, b1, O1, N);
  // Layer 2
  gemm_k<<<N / 32, 256, 0, stream>>>(O1, W2, Hb);
  agg_k<<<(N + NPB - 1) / NPB, 256, 0, stream>>>(Hb, normv, row_start, esrc, b2, out, N);
}

// Round 2
// 451.325 us; speedup vs baseline: 1.2587x; 1.2587x over previous
//
#include <hip/hip_runtime.h>

#define D 128

// ---- CSR build ----------------------------------------------------------

// Pass 1: degree count; atomicAdd's return value is the edge's rank within
// its destination row (removes the atomic from the fill pass).
__global__ __launch_bounds__(256) void count_k(const int* __restrict__ dst,
                                               int* __restrict__ deg,
                                               int* __restrict__ rank, int E) {
  int e = blockIdx.x * 256 + threadIdx.x;
  if (e < E) rank[e] = atomicAdd(&deg[dst[e]], 1);
}

__global__ __launch_bounds__(256) void norm_k(const int* __restrict__ deg,
                                              float* __restrict__ nrm,
                                              int* __restrict__ row_start,
                                              int N, int E) {
  int i = blockIdx.x * 256 + threadIdx.x;
  if (i < N) nrm[i] = rsqrtf((float)deg[i] + 1.0f);
  if (i == 0) row_start[N] = E;
}

__global__ __launch_bounds__(256) void bsum_k(const int* __restrict__ deg,
                                              int* __restrict__ bsum, int N) {
  __shared__ int s[256];
  int t = threadIdx.x, i = blockIdx.x * 256 + t;
  s[t] = (i < N) ? deg[i] : 0;
  __syncthreads();
  for (int off = 128; off > 0; off >>= 1) {
    if (t < off) s[t] += s[t + off];
    __syncthreads();
  }
  if (t == 0) bsum[blockIdx.x] = s[0];
}

__global__ __launch_bounds__(512) void bscan_k(int* bsum, int nb) {
  __shared__ int s[512];
  int t = threadIdx.x;
  s[t] = (t < nb) ? bsum[t] : 0;
  __syncthreads();
  for (int off = 1; off < 512; off <<= 1) {
    int v = (t >= off) ? s[t - off] : 0;
    __syncthreads();
    s[t] += v;
    __syncthreads();
  }
  if (t < nb) bsum[t] = s[t];
}

__global__ __launch_bounds__(256) void scanfin_k(const int* __restrict__ deg,
                                                 const int* __restrict__ bsum_incl,
                                                 int* __restrict__ row_start, int N) {
  __shared__ int s[256];
  int b = blockIdx.x, t = threadIdx.x, i = b * 256 + t;
  int v0 = (i < N) ? deg[i] : 0;
  s[t] = v0;
  __syncthreads();
  for (int off = 1; off < 256; off <<= 1) {
    int v = (t >= off) ? s[t - off] : 0;
    __syncthreads();
    s[t] += v;
    __syncthreads();
  }
  int base = (b > 0) ? bsum_incl[b - 1] : 0;
  if (i < N) row_start[i] = base + s[t] - v0;
}

__global__ __launch_bounds__(256) void fill_k(const int* __restrict__ src,
                                              const int* __restrict__ dst,
                                              const int* __restrict__ row_start,
                                              const int* __restrict__ rank,
                                              int* __restrict__ esrc, int E) {
  int e = blockIdx.x * 256 + threadIdx.x;
  if (e < E) esrc[row_start[dst[e]] + rank[e]] = src[e];
}

// ---- GEMM + norm fuse: Hn = (X @ W) * nrm[row] --------------------------
// Block: 128 rows x 128 cols, 256 threads, 8x8 register tile.
// K staged in 4 chunks of 32. XsT stored transposed (pitch 132 for b128
// alignment; staging writes 4-way conflict, inner reads broadcast-free).
__global__ __launch_bounds__(256) void gemm_k(const float* __restrict__ X,
                                              const float* __restrict__ W,
                                              const float* __restrict__ nrm,
                                              float* __restrict__ Hn, int N) {
  __shared__ float XsT[32][132];
  __shared__ float Ws[32][128];
  int tid = threadIdx.x;
  int row0 = blockIdx.x * 128;
  int cq = tid & 15;        // column group 0..15
  int rg = tid >> 4;        // row group 0..15
  int r0 = rg * 8;          // rows r0..r0+7
  int c0 = cq * 4;          // cols c0..c0+3 and c0+64..c0+67
  float acc[8][8] = {};

  for (int ks = 0; ks < 4; ++ks) {
    __syncthreads();
    {  // stage W rows [ks*32, ks*32+32): 1024 float4, linear, conflict-free
      const float4* W4 = (const float4*)(W + ks * 32 * D);
      float4* Ws4 = (float4*)&Ws[0][0];
#pragma unroll
      for (int it = 0; it < 4; ++it) Ws4[it * 256 + tid] = W4[it * 256 + tid];
    }
    {  // stage X tile transposed: 128 rows x 32 k
#pragma unroll
      for (int it = 0; it < 4; ++it) {
        int idx = it * 256 + tid;
        int r = idx >> 3, kq = idx & 7;
        int grow = row0 + r;
        float4 v = make_float4(0.f, 0.f, 0.f, 0.f);
        if (grow < N) v = *(const float4*)&X[(size_t)grow * D + ks * 32 + kq * 4];
        XsT[kq * 4 + 0][r] = v.x;
        XsT[kq * 4 + 1][r] = v.y;
        XsT[kq * 4 + 2][r] = v.z;
        XsT[kq * 4 + 3][r] = v.w;
      }
    }
    __syncthreads();
#pragma unroll 4
    for (int k = 0; k < 32; ++k) {
      float xr[8], wc[8];
      *(float4*)&xr[0] = *(const float4*)&XsT[k][r0];
      *(float4*)&xr[4] = *(const float4*)&XsT[k][r0 + 4];
      *(float4*)&wc[0] = *(const float4*)&Ws[k][c0];
      *(float4*)&wc[4] = *(const float4*)&Ws[k][c0 + 64];
#pragma unroll
      for (int rr = 0; rr < 8; ++rr)
#pragma unroll
        for (int cc = 0; cc < 8; ++cc)
          acc[rr][cc] += xr[rr] * wc[cc];
    }
  }

#pragma unroll
  for (int rr = 0; rr < 8; ++rr) {
    int grow = row0 + r0 + rr;
    if (grow < N) {
      float nn = nrm[grow];
      float4 v0, v1;
      v0.x = acc[rr][0] * nn; v0.y = acc[rr][1] * nn;
      v0.z = acc[rr][2] * nn; v0.w = acc[rr][3] * nn;
      v1.x = acc[rr][4] * nn; v1.y = acc[rr][5] * nn;
      v1.z = acc[rr][6] * nn; v1.w = acc[rr][7] * nn;
      *(float4*)&Hn[(size_t)grow * D + c0] = v0;
      *(float4*)&Hn[(size_t)grow * D + c0 + 64] = v1;
    }
  }
}

// ---- Fused aggregate + self-loop + bias + ReLU --------------------------
// out[n] = relu(nrm[n] * (sum_{src in row n} Hn[src] + Hn[n]) + b)
// One wave per node, lane owns 2 dims; 4 independent gather chains in flight.
__global__ __launch_bounds__(256) void agg_k(const float* __restrict__ Hn,
                                             const float* __restrict__ nrm,
                                             const int* __restrict__ row_start,
                                             const int* __restrict__ esrc,
                                             const float* __restrict__ bias,
                                             float* __restrict__ out, int N) {
  int wave = threadIdx.x >> 6, lane = threadIdx.x & 63;
  int n = blockIdx.x * 4 + wave;
  if (n >= N) return;
  int d = lane * 2;
  int i = row_start[n], end = row_start[n + 1];
  float ax0 = 0.f, ay0 = 0.f, ax1 = 0.f, ay1 = 0.f;
  float ax2 = 0.f, ay2 = 0.f, ax3 = 0.f, ay3 = 0.f;
  for (; i + 3 < end; i += 4) {
    int s0 = esrc[i], s1 = esrc[i + 1], s2 = esrc[i + 2], s3 = esrc[i + 3];
    float2 h0 = *(const float2*)&Hn[(size_t)s0 * D + d];
    float2 h1 = *(const float2*)&Hn[(size_t)s1 * D + d];
    float2 h2 = *(const float2*)&Hn[(size_t)s2 * D + d];
    float2 h3 = *(const float2*)&Hn[(size_t)s3 * D + d];
    ax0 += h0.x; ay0 += h0.y;
    ax1 += h1.x; ay1 += h1.y;
    ax2 += h2.x; ay2 += h2.y;
    ax3 += h3.x; ay3 += h3.y;
  }
  for (; i < end; ++i) {
    int s0 = esrc[i];
    float2 h0 = *(const float2*)&Hn[(size_t)s0 * D + d];
    ax0 += h0.x; ay0 += h0.y;
  }
  float ax = (ax0 + ax1) + (ax2 + ax3);
  float ay = (ay0 + ay1) + (ay2 + ay3);
  float2 hn = *(const float2*)&Hn[(size_t)n * D + d];
  float2 bv = *(const float2*)&bias[d];
  float nn = nrm[n];
  float2 o;
  o.x = fmaxf((ax + hn.x) * nn + bv.x, 0.f);
  o.y = fmaxf((ay + hn.y) * nn + bv.y, 0.f);
  *(float2*)&out[(size_t)n * D + d] = o;
}

// ---- launch -------------------------------------------------------------

extern "C" void kernel_launch(void* const* d_in, const int* in_sizes, int n_in,
                              void* d_out, int out_size, void* d_ws, size_t ws_size,
                              hipStream_t stream) {
  const float* x  = (const float*)d_in[0];
  const int*   ei = (const int*)d_in[1];
  const float* W1 = (const float*)d_in[2];
  const float* b1 = (const float*)d_in[3];
  const float* W2 = (const float*)d_in[4];
  const float* b2 = (const float*)d_in[5];
  float* out = (float*)d_out;

  int N = in_sizes[0] / D;   // 100000
  int E = in_sizes[1] / 2;   // 1600000
  const int* srcp = ei;
  const int* dstp = ei + E;

  char* ws = (char*)d_ws;
  size_t off = 0;
  auto alloc = [&](size_t bytes) -> char* {
    char* p = ws + off;
    off = (off + bytes + 511) & ~(size_t)511;
    return p;
  };
  float* Hb        = (float*)alloc((size_t)N * D * 4);   // 51.2 MB
  float* O1        = (float*)alloc((size_t)N * D * 4);   // 51.2 MB
  float* normv     = (float*)alloc((size_t)N * 4);
  int*   deg       = (int*)alloc((size_t)N * 4);
  int*   row_start = (int*)alloc((size_t)(N + 1) * 4);
  int*   rank      = (int*)alloc((size_t)E * 4);         // 6.4 MB
  int*   esrc      = (int*)alloc((size_t)E * 4);         // 6.4 MB
  int*   bsum      = (int*)alloc(4096);

  int nbN = (N + 255) / 256;  // 391 (<= 512 for bscan_k)
  int nbE = (E + 255) / 256;  // 6250
  int nbG = (N + 127) / 128;  // 782

  hipMemsetAsync(deg, 0, (size_t)N * 4, stream);

  count_k<<<nbE, 256, 0, stream>>>(dstp, deg, rank, E);
  norm_k<<<nbN, 256, 0, stream>>>(deg, normv, row_start, N, E);
  bsum_k<<<nbN, 256, 0, stream>>>(deg, bsum, N);
  bscan_k<<<1, 512, 0, stream>>>(bsum, nbN);
  scanfin_k<<<nbN, 256, 0, stream>>>(deg, bsum, row_start, N);
  fill_k<<<nbE, 256, 0, stream>>>(srcp, dstp, row_start, rank, esrc, E);

  // Layer 1
  gemm_k<<<nbG, 256, 0, stream>>>(x, W1, normv, Hb, N);
  agg_k<<<(N + 3) / 4, 256, 0, stream>>>(Hb, normv, row_start, esrc, b1, O1, N);
  // Layer 2
  gemm_k<<<nbG, 256, 0, stream>>>(O1, W2, normv, Hb, N);
  agg_k<<<(N + 3) / 4, 256, 0, stream>>>(Hb, normv, row_start, esrc, b2, out, N);
}

// Round 3
// 353.612 us; speedup vs baseline: 1.6065x; 1.2763x over previous
//
#include <hip/hip_runtime.h>

#define D 128

typedef _Float16 half4 __attribute__((ext_vector_type(4)));

// ---- CSR build ----------------------------------------------------------

__global__ __launch_bounds__(256) void count_k(const int* __restrict__ dst,
                                               int* __restrict__ deg,
                                               int* __restrict__ rank, int E) {
  int e = blockIdx.x * 256 + threadIdx.x;
  if (e < E) rank[e] = atomicAdd(&deg[dst[e]], 1);
}

__global__ __launch_bounds__(256) void norm_k(const int* __restrict__ deg,
                                              float* __restrict__ nrm,
                                              int* __restrict__ row_start,
                                              int N, int E) {
  int i = blockIdx.x * 256 + threadIdx.x;
  if (i < N) nrm[i] = rsqrtf((float)deg[i] + 1.0f);
  if (i == 0) row_start[N] = E;
}

__global__ __launch_bounds__(256) void bsum_k(const int* __restrict__ deg,
                                              int* __restrict__ bsum, int N) {
  __shared__ int s[256];
  int t = threadIdx.x, i = blockIdx.x * 256 + t;
  s[t] = (i < N) ? deg[i] : 0;
  __syncthreads();
  for (int off = 128; off > 0; off >>= 1) {
    if (t < off) s[t] += s[t + off];
    __syncthreads();
  }
  if (t == 0) bsum[blockIdx.x] = s[0];
}

__global__ __launch_bounds__(512) void bscan_k(int* bsum, int nb) {
  __shared__ int s[512];
  int t = threadIdx.x;
  s[t] = (t < nb) ? bsum[t] : 0;
  __syncthreads();
  for (int off = 1; off < 512; off <<= 1) {
    int v = (t >= off) ? s[t - off] : 0;
    __syncthreads();
    s[t] += v;
    __syncthreads();
  }
  if (t < nb) bsum[t] = s[t];
}

__global__ __launch_bounds__(256) void scanfin_k(const int* __restrict__ deg,
                                                 const int* __restrict__ bsum_incl,
                                                 int* __restrict__ row_start, int N) {
  __shared__ int s[256];
  int b = blockIdx.x, t = threadIdx.x, i = b * 256 + t;
  int v0 = (i < N) ? deg[i] : 0;
  s[t] = v0;
  __syncthreads();
  for (int off = 1; off < 256; off <<= 1) {
    int v = (t >= off) ? s[t - off] : 0;
    __syncthreads();
    s[t] += v;
    __syncthreads();
  }
  int base = (b > 0) ? bsum_incl[b - 1] : 0;
  if (i < N) row_start[i] = base + s[t] - v0;
}

__global__ __launch_bounds__(256) void fill_k(const int* __restrict__ src,
                                              const int* __restrict__ dst,
                                              const int* __restrict__ row_start,
                                              const int* __restrict__ rank,
                                              int* __restrict__ esrc, int E) {
  int e = blockIdx.x * 256 + threadIdx.x;
  if (e < E) esrc[row_start[dst[e]] + rank[e]] = src[e];
}

// ---- GEMM + norm fuse: Hh = fp16((X @ W) * nrm[row]) --------------------
// Block: 128 rows x 128 cols, 256 threads, 8x8 register tile.
__global__ __launch_bounds__(256) void gemm_k(const float* __restrict__ X,
                                              const float* __restrict__ W,
                                              const float* __restrict__ nrm,
                                              _Float16* __restrict__ Hh, int N) {
  __shared__ float XsT[32][132];
  __shared__ float Ws[32][128];
  int tid = threadIdx.x;
  int row0 = blockIdx.x * 128;
  int cq = tid & 15;
  int rg = tid >> 4;
  int r0 = rg * 8;
  int c0 = cq * 4;
  float acc[8][8] = {};

  for (int ks = 0; ks < 4; ++ks) {
    __syncthreads();
    {  // stage W rows [ks*32, ks*32+32)
      const float4* W4 = (const float4*)(W + ks * 32 * D);
      float4* Ws4 = (float4*)&Ws[0][0];
#pragma unroll
      for (int it = 0; it < 4; ++it) Ws4[it * 256 + tid] = W4[it * 256 + tid];
    }
    {  // stage X tile transposed
#pragma unroll
      for (int it = 0; it < 4; ++it) {
        int idx = it * 256 + tid;
        int r = idx >> 3, kq = idx & 7;
        int grow = row0 + r;
        float4 v = make_float4(0.f, 0.f, 0.f, 0.f);
        if (grow < N) v = *(const float4*)&X[(size_t)grow * D + ks * 32 + kq * 4];
        XsT[kq * 4 + 0][r] = v.x;
        XsT[kq * 4 + 1][r] = v.y;
        XsT[kq * 4 + 2][r] = v.z;
        XsT[kq * 4 + 3][r] = v.w;
      }
    }
    __syncthreads();
#pragma unroll 4
    for (int k = 0; k < 32; ++k) {
      float xr[8], wc[8];
      *(float4*)&xr[0] = *(const float4*)&XsT[k][r0];
      *(float4*)&xr[4] = *(const float4*)&XsT[k][r0 + 4];
      *(float4*)&wc[0] = *(const float4*)&Ws[k][c0];
      *(float4*)&wc[4] = *(const float4*)&Ws[k][c0 + 64];
#pragma unroll
      for (int rr = 0; rr < 8; ++rr)
#pragma unroll
        for (int cc = 0; cc < 8; ++cc)
          acc[rr][cc] += xr[rr] * wc[cc];
    }
  }

#pragma unroll
  for (int rr = 0; rr < 8; ++rr) {
    int grow = row0 + r0 + rr;
    if (grow < N) {
      float nn = nrm[grow];
      half4 v0, v1;
#pragma unroll
      for (int j = 0; j < 4; ++j) {
        v0[j] = (_Float16)(acc[rr][j] * nn);
        v1[j] = (_Float16)(acc[rr][j + 4] * nn);
      }
      *(half4*)&Hh[(size_t)grow * D + c0] = v0;
      *(half4*)&Hh[(size_t)grow * D + c0 + 64] = v1;
    }
  }
}

// ---- Fused aggregate + self-loop + bias + ReLU --------------------------
// out[n] = relu(nrm[n] * (sum_{src in row n} Hh[src] + Hh[n]) + b)
// One wave per node. Half-wave (32 lanes x 8B) reads one full 256B fp16 row;
// 4 chains x 2 halves = 8 edges in flight. Cross-half combine via shfl_xor(32).
__global__ __launch_bounds__(256) void agg_k(const _Float16* __restrict__ Hh,
                                             const float* __restrict__ nrm,
                                             const int* __restrict__ row_start,
                                             const int* __restrict__ esrc,
                                             const float* __restrict__ bias,
                                             float* __restrict__ out, int N) {
  int wave = threadIdx.x >> 6, lane = threadIdx.x & 63;
  int n = blockIdx.x * 4 + wave;
  if (n >= N) return;
  int half = lane >> 5, sub = lane & 31;
  int d = sub * 4;
  int i = row_start[n], end = row_start[n + 1];

  float4 a0 = {0, 0, 0, 0}, a1 = {0, 0, 0, 0}, a2 = {0, 0, 0, 0}, a3 = {0, 0, 0, 0};
  for (; i + 8 <= end; i += 8) {
    int s0 = esrc[i + half];
    int s1 = esrc[i + 2 + half];
    int s2 = esrc[i + 4 + half];
    int s3 = esrc[i + 6 + half];
    half4 v0 = *(const half4*)&Hh[(size_t)s0 * D + d];
    half4 v1 = *(const half4*)&Hh[(size_t)s1 * D + d];
    half4 v2 = *(const half4*)&Hh[(size_t)s2 * D + d];
    half4 v3 = *(const half4*)&Hh[(size_t)s3 * D + d];
    a0.x += (float)v0[0]; a0.y += (float)v0[1]; a0.z += (float)v0[2]; a0.w += (float)v0[3];
    a1.x += (float)v1[0]; a1.y += (float)v1[1]; a1.z += (float)v1[2]; a1.w += (float)v1[3];
    a2.x += (float)v2[0]; a2.y += (float)v2[1]; a2.z += (float)v2[2]; a2.w += (float)v2[3];
    a3.x += (float)v3[0]; a3.y += (float)v3[1]; a3.z += (float)v3[2]; a3.w += (float)v3[3];
  }
  for (; i + half < end; i += 2) {
    int s0 = esrc[i + half];
    half4 v0 = *(const half4*)&Hh[(size_t)s0 * D + d];
    a0.x += (float)v0[0]; a0.y += (float)v0[1]; a0.z += (float)v0[2]; a0.w += (float)v0[3];
  }

  float f0 = (a0.x + a1.x) + (a2.x + a3.x);
  float f1 = (a0.y + a1.y) + (a2.y + a3.y);
  float f2 = (a0.z + a1.z) + (a2.z + a3.z);
  float f3 = (a0.w + a1.w) + (a2.w + a3.w);
  f0 += __shfl_xor(f0, 32);
  f1 += __shfl_xor(f1, 32);
  f2 += __shfl_xor(f2, 32);
  f3 += __shfl_xor(f3, 32);

  if (half == 0) {
    half4 hv = *(const half4*)&Hh[(size_t)n * D + d];
    float4 bv = *(const float4*)&bias[d];
    float nn = nrm[n];
    float4 o;
    o.x = fmaxf((f0 + (float)hv[0]) * nn + bv.x, 0.f);
    o.y = fmaxf((f1 + (float)hv[1]) * nn + bv.y, 0.f);
    o.z = fmaxf((f2 + (float)hv[2]) * nn + bv.z, 0.f);
    o.w = fmaxf((f3 + (float)hv[3]) * nn + bv.w, 0.f);
    *(float4*)&out[(size_t)n * D + d] = o;
  }
}

// ---- launch -------------------------------------------------------------

extern "C" void kernel_launch(void* const* d_in, const int* in_sizes, int n_in,
                              void* d_out, int out_size, void* d_ws, size_t ws_size,
                              hipStream_t stream) {
  const float* x  = (const float*)d_in[0];
  const int*   ei = (const int*)d_in[1];
  const float* W1 = (const float*)d_in[2];
  const float* b1 = (const float*)d_in[3];
  const float* W2 = (const float*)d_in[4];
  const float* b2 = (const float*)d_in[5];
  float* out = (float*)d_out;

  int N = in_sizes[0] / D;   // 100000
  int E = in_sizes[1] / 2;   // 1600000
  const int* srcp = ei;
  const int* dstp = ei + E;

  char* ws = (char*)d_ws;
  size_t off = 0;
  auto alloc = [&](size_t bytes) -> char* {
    char* p = ws + off;
    off = (off + bytes + 511) & ~(size_t)511;
    return p;
  };
  _Float16* Hh     = (_Float16*)alloc((size_t)N * D * 2);  // 25.6 MB
  float* O1        = (float*)alloc((size_t)N * D * 4);     // 51.2 MB
  float* normv     = (float*)alloc((size_t)N * 4);
  int*   deg       = (int*)alloc((size_t)N * 4);
  int*   row_start = (int*)alloc((size_t)(N + 1) * 4);
  int*   rank      = (int*)alloc((size_t)E * 4);           // 6.4 MB
  int*   esrc      = (int*)alloc((size_t)E * 4);           // 6.4 MB
  int*   bsum      = (int*)alloc(4096);

  int nbN = (N + 255) / 256;  // 391 (<= 512 for bscan_k)
  int nbE = (E + 255) / 256;  // 6250
  int nbG = (N + 127) / 128;  // 782

  hipMemsetAsync(deg, 0, (size_t)N * 4, stream);

  count_k<<<nbE, 256, 0, stream>>>(dstp, deg, rank, E);
  norm_k<<<nbN, 256, 0, stream>>>(deg, normv, row_start, N, E);
  bsum_k<<<nbN, 256, 0, stream>>>(deg, bsum, N);
  bscan_k<<<1, 512, 0, stream>>>(bsum, nbN);
  scanfin_k<<<nbN, 256, 0, stream>>>(deg, bsum, row_start, N);
  fill_k<<<nbE, 256, 0, stream>>>(srcp, dstp, row_start, rank, esrc, E);

  // Layer 1
  gemm_k<<<nbG, 256, 0, stream>>>(x, W1, normv, Hh, N);
  agg_k<<<(N + 3) / 4, 256, 0, stream>>>(Hh, normv, row_start, esrc, b1, O1, N);
  // Layer 2
  gemm_k<<<nbG, 256, 0, stream>>>(O1, W2, normv, Hh, N);
  agg_k<<<(N + 3) / 4, 256, 0, stream>>>(Hh, normv, row_start, esrc, b2, out, N);
}

// Round 4
// 290.930 us; speedup vs baseline: 1.9526x; 1.2155x over previous
//
#include <hip/hip_runtime.h>

#define D 128
#define EG 4096   // edges per hist/scatter block

typedef _Float16 half4 __attribute__((ext_vector_type(4)));

// ---- CSR build via two-level LDS counting sort (no global atomics) ------

// Phase 1: per-group histogram over dst-buckets (bucket = dst >> 8).
__global__ __launch_bounds__(256) void hist_k(const int* __restrict__ dst,
                                              int* __restrict__ counts,
                                              int E, int NB, int G) {
  __shared__ int hist[512];
  int g = blockIdx.x, t = threadIdx.x;
  for (int b = t; b < NB; b += 256) hist[b] = 0;
  __syncthreads();
  int e0 = g * EG;
#pragma unroll
  for (int it = 0; it < EG / 256; ++it) {
    int e = e0 + it * 256 + t;
    if (e < E) atomicAdd(&hist[dst[e] >> 8], 1);
  }
  __syncthreads();
  for (int b = t; b < NB; b += 256) counts[b * G + g] = hist[b];
}

// Generic 3-kernel exclusive scan over M ints (M <= 1024*256).
__global__ __launch_bounds__(256) void bsum_k(const int* __restrict__ in,
                                              int* __restrict__ bsum, int M) {
  __shared__ int s[256];
  int t = threadIdx.x, i = blockIdx.x * 256 + t;
  s[t] = (i < M) ? in[i] : 0;
  __syncthreads();
  for (int off = 128; off > 0; off >>= 1) {
    if (t < off) s[t] += s[t + off];
    __syncthreads();
  }
  if (t == 0) bsum[blockIdx.x] = s[0];
}

__global__ __launch_bounds__(1024) void bscan_k(int* bsum, int nb) {
  __shared__ int s[1024];
  int t = threadIdx.x;
  s[t] = (t < nb) ? bsum[t] : 0;
  __syncthreads();
  for (int off = 1; off < 1024; off <<= 1) {
    int v = (t >= off) ? s[t - off] : 0;
    __syncthreads();
    s[t] += v;
    __syncthreads();
  }
  if (t < nb) bsum[t] = s[t];
}

__global__ __launch_bounds__(256) void scanfin_k(const int* __restrict__ in,
                                                 const int* __restrict__ bsum_incl,
                                                 int* __restrict__ outx, int M) {
  __shared__ int s[256];
  int b = blockIdx.x, t = threadIdx.x, i = b * 256 + t;
  int v0 = (i < M) ? in[i] : 0;
  s[t] = v0;
  __syncthreads();
  for (int off = 1; off < 256; off <<= 1) {
    int v = (t >= off) ? s[t - off] : 0;
    __syncthreads();
    s[t] += v;
    __syncthreads();
  }
  int base = (b > 0) ? bsum_incl[b - 1] : 0;
  if (i < M) outx[i] = base + s[t] - v0;  // exclusive scan
}

// Phase 3: scatter edges into bucket-partitioned tmp (packed dstlo|src).
__global__ __launch_bounds__(256) void scatter_k(const int* __restrict__ src,
                                                 const int* __restrict__ dst,
                                                 const int* __restrict__ cscan,
                                                 unsigned* __restrict__ tmp,
                                                 int E, int NB, int G) {
  __shared__ int hist[512];
  __shared__ int base[512];
  int g = blockIdx.x, t = threadIdx.x;
  for (int b = t; b < NB; b += 256) {
    hist[b] = 0;
    base[b] = cscan[b * G + g];
  }
  __syncthreads();
  int e0 = g * EG;
#pragma unroll
  for (int it = 0; it < EG / 256; ++it) {
    int e = e0 + it * 256 + t;
    if (e < E) {
      int d = dst[e];
      int b = d >> 8;
      int r = atomicAdd(&hist[b], 1);
      tmp[base[b] + r] = ((unsigned)(d & 255) << 20) | (unsigned)src[e];
    }
  }
}

// Phase 4: per-bucket local count/scan/rank; emits deg->norm, row_start, esrc.
__global__ __launch_bounds__(256) void bucket_k(const unsigned* __restrict__ tmp,
                                                const int* __restrict__ cscan,
                                                float* __restrict__ nrm,
                                                int* __restrict__ row_start,
                                                int* __restrict__ esrc,
                                                int N, int E, int NB, int G) {
  __shared__ int cnt[256];
  __shared__ int sc[256];
  __shared__ int cur[256];
  int b = blockIdx.x, t = threadIdx.x;
  int seg0 = cscan[b * G];
  int seg1 = (b == NB - 1) ? E : cscan[(b + 1) * G];
  cnt[t] = 0;
  __syncthreads();
  for (int i = seg0 + t; i < seg1; i += 256)
    atomicAdd(&cnt[tmp[i] >> 20], 1);
  __syncthreads();
  int v0 = cnt[t];
  sc[t] = v0;
  __syncthreads();
  for (int off = 1; off < 256; off <<= 1) {
    int v = (t >= off) ? sc[t - off] : 0;
    __syncthreads();
    sc[t] += v;
    __syncthreads();
  }
  int ex = sc[t] - v0;  // exclusive within bucket
  cur[t] = ex;
  int node = b * 256 + t;
  if (node < N) {
    row_start[node] = seg0 + ex;
    nrm[node] = rsqrtf((float)v0 + 1.0f);
  }
  if (b == 0 && t == 0) row_start[N] = E;
  __syncthreads();
  for (int i = seg0 + t; i < seg1; i += 256) {
    unsigned p = tmp[i];
    int r = atomicAdd(&cur[p >> 20], 1);
    esrc[seg0 + r] = (int)(p & 0xFFFFF);
  }
}

// ---- GEMM + norm fuse: Hh = fp16((X @ W) * nrm[row]) --------------------
__global__ __launch_bounds__(256) void gemm_k(const float* __restrict__ X,
                                              const float* __restrict__ W,
                                              const float* __restrict__ nrm,
                                              _Float16* __restrict__ Hh, int N) {
  __shared__ float XsT[32][132];
  __shared__ float Ws[32][128];
  int tid = threadIdx.x;
  int row0 = blockIdx.x * 128;
  int cq = tid & 15;
  int rg = tid >> 4;
  int r0 = rg * 8;
  int c0 = cq * 4;
  float acc[8][8] = {};

  for (int ks = 0; ks < 4; ++ks) {
    __syncthreads();
    {
      const float4* W4 = (const float4*)(W + ks * 32 * D);
      float4* Ws4 = (float4*)&Ws[0][0];
#pragma unroll
      for (int it = 0; it < 4; ++it) Ws4[it * 256 + tid] = W4[it * 256 + tid];
    }
    {
#pragma unroll
      for (int it = 0; it < 4; ++it) {
        int idx = it * 256 + tid;
        int r = idx >> 3, kq = idx & 7;
        int grow = row0 + r;
        float4 v = make_float4(0.f, 0.f, 0.f, 0.f);
        if (grow < N) v = *(const float4*)&X[(size_t)grow * D + ks * 32 + kq * 4];
        XsT[kq * 4 + 0][r] = v.x;
        XsT[kq * 4 + 1][r] = v.y;
        XsT[kq * 4 + 2][r] = v.z;
        XsT[kq * 4 + 3][r] = v.w;
      }
    }
    __syncthreads();
#pragma unroll 4
    for (int k = 0; k < 32; ++k) {
      float xr[8], wc[8];
      *(float4*)&xr[0] = *(const float4*)&XsT[k][r0];
      *(float4*)&xr[4] = *(const float4*)&XsT[k][r0 + 4];
      *(float4*)&wc[0] = *(const float4*)&Ws[k][c0];
      *(float4*)&wc[4] = *(const float4*)&Ws[k][c0 + 64];
#pragma unroll
      for (int rr = 0; rr < 8; ++rr)
#pragma unroll
        for (int cc = 0; cc < 8; ++cc)
          acc[rr][cc] += xr[rr] * wc[cc];
    }
  }

#pragma unroll
  for (int rr = 0; rr < 8; ++rr) {
    int grow = row0 + r0 + rr;
    if (grow < N) {
      float nn = nrm[grow];
      half4 v0, v1;
#pragma unroll
      for (int j = 0; j < 4; ++j) {
        v0[j] = (_Float16)(acc[rr][j] * nn);
        v1[j] = (_Float16)(acc[rr][j + 4] * nn);
      }
      *(half4*)&Hh[(size_t)grow * D + c0] = v0;
      *(half4*)&Hh[(size_t)grow * D + c0 + 64] = v1;
    }
  }
}

// ---- Fused aggregate + self-loop + bias + ReLU --------------------------
__global__ __launch_bounds__(256) void agg_k(const _Float16* __restrict__ Hh,
                                             const float* __restrict__ nrm,
                                             const int* __restrict__ row_start,
                                             const int* __restrict__ esrc,
                                             const float* __restrict__ bias,
                                             float* __restrict__ out, int N) {
  int wave = threadIdx.x >> 6, lane = threadIdx.x & 63;
  int n = blockIdx.x * 4 + wave;
  if (n >= N) return;
  int half = lane >> 5, sub = lane & 31;
  int d = sub * 4;
  int i = row_start[n], end = row_start[n + 1];

  float4 a0 = {0, 0, 0, 0}, a1 = {0, 0, 0, 0}, a2 = {0, 0, 0, 0}, a3 = {0, 0, 0, 0};
  for (; i + 8 <= end; i += 8) {
    int s0 = esrc[i + half];
    int s1 = esrc[i + 2 + half];
    int s2 = esrc[i + 4 + half];
    int s3 = esrc[i + 6 + half];
    half4 v0 = *(const half4*)&Hh[(size_t)s0 * D + d];
    half4 v1 = *(const half4*)&Hh[(size_t)s1 * D + d];
    half4 v2 = *(const half4*)&Hh[(size_t)s2 * D + d];
    half4 v3 = *(const half4*)&Hh[(size_t)s3 * D + d];
    a0.x += (float)v0[0]; a0.y += (float)v0[1]; a0.z += (float)v0[2]; a0.w += (float)v0[3];
    a1.x += (float)v1[0]; a1.y += (float)v1[1]; a1.z += (float)v1[2]; a1.w += (float)v1[3];
    a2.x += (float)v2[0]; a2.y += (float)v2[1]; a2.z += (float)v2[2]; a2.w += (float)v2[3];
    a3.x += (float)v3[0]; a3.y += (float)v3[1]; a3.z += (float)v3[2]; a3.w += (float)v3[3];
  }
  for (; i + half < end; i += 2) {
    int s0 = esrc[i + half];
    half4 v0 = *(const half4*)&Hh[(size_t)s0 * D + d];
    a0.x += (float)v0[0]; a0.y += (float)v0[1]; a0.z += (float)v0[2]; a0.w += (float)v0[3];
  }

  float f0 = (a0.x + a1.x) + (a2.x + a3.x);
  float f1 = (a0.y + a1.y) + (a2.y + a3.y);
  float f2 = (a0.z + a1.z) + (a2.z + a3.z);
  float f3 = (a0.w + a1.w) + (a2.w + a3.w);
  f0 += __shfl_xor(f0, 32);
  f1 += __shfl_xor(f1, 32);
  f2 += __shfl_xor(f2, 32);
  f3 += __shfl_xor(f3, 32);

  if (half == 0) {
    half4 hv = *(const half4*)&Hh[(size_t)n * D + d];
    float4 bv = *(const float4*)&bias[d];
    float nn = nrm[n];
    float4 o;
    o.x = fmaxf((f0 + (float)hv[0]) * nn + bv.x, 0.f);
    o.y = fmaxf((f1 + (float)hv[1]) * nn + bv.y, 0.f);
    o.z = fmaxf((f2 + (float)hv[2]) * nn + bv.z, 0.f);
    o.w = fmaxf((f3 + (float)hv[3]) * nn + bv.w, 0.f);
    *(float4*)&out[(size_t)n * D + d] = o;
  }
}

// ---- launch -------------------------------------------------------------

extern "C" void kernel_launch(void* const* d_in, const int* in_sizes, int n_in,
                              void* d_out, int out_size, void* d_ws, size_t ws_size,
                              hipStream_t stream) {
  const float* x  = (const float*)d_in[0];
  const int*   ei = (const int*)d_in[1];
  const float* W1 = (const float*)d_in[2];
  const float* b1 = (const float*)d_in[3];
  const float* W2 = (const float*)d_in[4];
  const float* b2 = (const float*)d_in[5];
  float* out = (float*)d_out;

  int N = in_sizes[0] / D;   // 100000
  int E = in_sizes[1] / 2;   // 1600000
  const int* srcp = ei;
  const int* dstp = ei + E;

  int NB = (N + 255) / 256;        // 391 dst-buckets (<= 512 for LDS arrays)
  int G  = (E + EG - 1) / EG;      // 391 edge groups
  int M  = NB * G;                 // counts matrix size
  int nbM = (M + 255) / 256;       // 598 (<= 1024 for bscan_k)

  char* ws = (char*)d_ws;
  size_t off = 0;
  auto alloc = [&](size_t bytes) -> char* {
    char* p = ws + off;
    off = (off + bytes + 511) & ~(size_t)511;
    return p;
  };
  _Float16* Hh     = (_Float16*)alloc((size_t)N * D * 2);  // 25.6 MB
  float* O1        = (float*)alloc((size_t)N * D * 4);     // 51.2 MB
  float* normv     = (float*)alloc((size_t)N * 4);
  int*   row_start = (int*)alloc((size_t)(N + 1) * 4);
  int*   counts    = (int*)alloc((size_t)M * 4);           // 0.6 MB
  int*   cscan     = (int*)alloc((size_t)M * 4);           // 0.6 MB
  unsigned* tmp    = (unsigned*)alloc((size_t)E * 4);      // 6.4 MB
  int*   esrc      = (int*)alloc((size_t)E * 4);           // 6.4 MB
  int*   bsum      = (int*)alloc(4096);

  int nbG = (N + 127) / 128;  // gemm blocks

  // CSR build (no global atomics)
  hist_k<<<G, 256, 0, stream>>>(dstp, counts, E, NB, G);
  bsum_k<<<nbM, 256, 0, stream>>>(counts, bsum, M);
  bscan_k<<<1, 1024, 0, stream>>>(bsum, nbM);
  scanfin_k<<<nbM, 256, 0, stream>>>(counts, bsum, cscan, M);
  scatter_k<<<G, 256, 0, stream>>>(srcp, dstp, cscan, tmp, E, NB, G);
  bucket_k<<<NB, 256, 0, stream>>>(tmp, cscan, normv, row_start, esrc, N, E, NB, G);

  // Layer 1
  gemm_k<<<nbG, 256, 0, stream>>>(x, W1, normv, Hh, N);
  agg_k<<<(N + 3) / 4, 256, 0, stream>>>(Hh, normv, row_start, esrc, b1, O1, N);
  // Layer 2
  gemm_k<<<nbG, 256, 0, stream>>>(O1, W2, normv, Hh, N);
  agg_k<<<(N + 3) / 4, 256, 0, stream>>>(Hh, normv, row_start, esrc, b2, out, N);
}

// Round 5
// 232.372 us; speedup vs baseline: 2.4446x; 1.2520x over previous
//
#include <hip/hip_runtime.h>

#define D 128
#define EG 4096   // edges per hist/scatter block

typedef _Float16 h8 __attribute__((ext_vector_type(8)));
typedef float f4 __attribute__((ext_vector_type(4)));

// ---- CSR build via two-level LDS counting sort (no global atomics) ------

__global__ __launch_bounds__(256) void hist_k(const int* __restrict__ dst,
                                              int* __restrict__ counts,
                                              int E, int NB, int G) {
  __shared__ int hist[512];
  int g = blockIdx.x, t = threadIdx.x;
  for (int b = t; b < NB; b += 256) hist[b] = 0;
  __syncthreads();
  int e0 = g * EG;
#pragma unroll
  for (int it = 0; it < EG / 256; ++it) {
    int e = e0 + it * 256 + t;
    if (e < E) atomicAdd(&hist[dst[e] >> 8], 1);
  }
  __syncthreads();
  for (int b = t; b < NB; b += 256) counts[b * G + g] = hist[b];
}

__global__ __launch_bounds__(256) void bsum_k(const int* __restrict__ in,
                                              int* __restrict__ bsum, int M) {
  __shared__ int s[256];
  int t = threadIdx.x, i = blockIdx.x * 256 + t;
  s[t] = (i < M) ? in[i] : 0;
  __syncthreads();
  for (int off = 128; off > 0; off >>= 1) {
    if (t < off) s[t] += s[t + off];
    __syncthreads();
  }
  if (t == 0) bsum[blockIdx.x] = s[0];
}

__global__ __launch_bounds__(1024) void bscan_k(int* bsum, int nb) {
  __shared__ int s[1024];
  int t = threadIdx.x;
  s[t] = (t < nb) ? bsum[t] : 0;
  __syncthreads();
  for (int off = 1; off < 1024; off <<= 1) {
    int v = (t >= off) ? s[t - off] : 0;
    __syncthreads();
    s[t] += v;
    __syncthreads();
  }
  if (t < nb) bsum[t] = s[t];
}

__global__ __launch_bounds__(256) void scanfin_k(const int* __restrict__ in,
                                                 const int* __restrict__ bsum_incl,
                                                 int* __restrict__ outx, int M) {
  __shared__ int s[256];
  int b = blockIdx.x, t = threadIdx.x, i = b * 256 + t;
  int v0 = (i < M) ? in[i] : 0;
  s[t] = v0;
  __syncthreads();
  for (int off = 1; off < 256; off <<= 1) {
    int v = (t >= off) ? s[t - off] : 0;
    __syncthreads();
    s[t] += v;
    __syncthreads();
  }
  int base = (b > 0) ? bsum_incl[b - 1] : 0;
  if (i < M) outx[i] = base + s[t] - v0;
}

__global__ __launch_bounds__(256) void scatter_k(const int* __restrict__ src,
                                                 const int* __restrict__ dst,
                                                 const int* __restrict__ cscan,
                                                 unsigned* __restrict__ tmp,
                                                 int E, int NB, int G) {
  __shared__ int hist[512];
  __shared__ int base[512];
  int g = blockIdx.x, t = threadIdx.x;
  for (int b = t; b < NB; b += 256) {
    hist[b] = 0;
    base[b] = cscan[b * G + g];
  }
  __syncthreads();
  int e0 = g * EG;
#pragma unroll
  for (int it = 0; it < EG / 256; ++it) {
    int e = e0 + it * 256 + t;
    if (e < E) {
      int d = dst[e];
      int b = d >> 8;
      int r = atomicAdd(&hist[b], 1);
      tmp[base[b] + r] = ((unsigned)(d & 255) << 20) | (unsigned)src[e];
    }
  }
}

__global__ __launch_bounds__(256) void bucket_k(const unsigned* __restrict__ tmp,
                                                const int* __restrict__ cscan,
                                                float* __restrict__ nrm,
                                                int* __restrict__ row_start,
                                                int* __restrict__ esrc,
                                                int N, int E, int NB, int G) {
  __shared__ int cnt[256];
  __shared__ int sc[256];
  __shared__ int cur[256];
  int b = blockIdx.x, t = threadIdx.x;
  int seg0 = cscan[b * G];
  int seg1 = (b == NB - 1) ? E : cscan[(b + 1) * G];
  cnt[t] = 0;
  __syncthreads();
  for (int i = seg0 + t; i < seg1; i += 256)
    atomicAdd(&cnt[tmp[i] >> 20], 1);
  __syncthreads();
  int v0 = cnt[t];
  sc[t] = v0;
  __syncthreads();
  for (int off = 1; off < 256; off <<= 1) {
    int v = (t >= off) ? sc[t - off] : 0;
    __syncthreads();
    sc[t] += v;
    __syncthreads();
  }
  int ex = sc[t] - v0;
  cur[t] = ex;
  int node = b * 256 + t;
  if (node < N) {
    row_start[node] = seg0 + ex;
    nrm[node] = rsqrtf((float)v0 + 1.0f);
  }
  if (b == 0 && t == 0) row_start[N] = E;
  __syncthreads();
  for (int i = seg0 + t; i < seg1; i += 256) {
    unsigned p = tmp[i];
    int r = atomicAdd(&cur[p >> 20], 1);
    esrc[seg0 + r] = (int)(p & 0xFFFFF);
  }
}

// ---- W transpose + fp16 convert: WT[col][k] = fp16(W[k][col]) -----------
__global__ __launch_bounds__(256) void wtrans_k(const float* __restrict__ W,
                                                _Float16* __restrict__ WT) {
  int idx = blockIdx.x * 256 + threadIdx.x;  // = k*128 + col, 16384 total
  int k = idx >> 7, col = idx & 127;
  WT[col * D + k] = (_Float16)W[idx];
}

// ---- MFMA GEMM + norm fuse: Hh = fp16((X @ W) * nrm[row]) ---------------
// 256 thr = 4 waves; wave computes 2 tiles of 16 rows x 128 cols.
// mfma_f32_16x16x32_f16: A row=lane&15, k=(lane>>4)*8+j; D col=lane&15,
// row=(lane>>4)*4+reg (m89-verified). W^T in LDS, pitch 136 (2-way conflicts only).
template <bool FP32IN>
__global__ __launch_bounds__(256) void gemm_k(const void* __restrict__ Xv,
                                              const _Float16* __restrict__ WT,
                                              const float* __restrict__ nrm,
                                              _Float16* __restrict__ Hh, int N) {
  __shared__ _Float16 Wl[D * 136];
  int tid = threadIdx.x;
#pragma unroll
  for (int it = 0; it < 8; ++it) {
    int idx = it * 256 + tid;        // 0..2047: col 0..127, kseg 0..15
    int col = idx >> 4, kseg = idx & 15;
    *(h8*)&Wl[col * 136 + kseg * 8] = *(const h8*)&WT[col * D + kseg * 8];
  }
  __syncthreads();
  int wave = tid >> 6, lane = tid & 63;
  int lr = lane & 15, lk = lane >> 4;
#pragma unroll
  for (int tt = 0; tt < 2; ++tt) {
    int tile = blockIdx.x * 8 + wave * 2 + tt;
    int row0 = tile * 16;
    if (row0 >= N) break;
    int row = row0 + lr;
    int rowc = row < N ? row : N - 1;
    h8 a[4];
    if constexpr (FP32IN) {
      const float* X = (const float*)Xv;
#pragma unroll
      for (int ks = 0; ks < 4; ++ks) {
        f4 p = *(const f4*)&X[(size_t)rowc * D + ks * 32 + lk * 8];
        f4 q = *(const f4*)&X[(size_t)rowc * D + ks * 32 + lk * 8 + 4];
        h8 t;
        t[0] = (_Float16)p[0]; t[1] = (_Float16)p[1];
        t[2] = (_Float16)p[2]; t[3] = (_Float16)p[3];
        t[4] = (_Float16)q[0]; t[5] = (_Float16)q[1];
        t[6] = (_Float16)q[2]; t[7] = (_Float16)q[3];
        a[ks] = t;
      }
    } else {
      const _Float16* X = (const _Float16*)Xv;
#pragma unroll
      for (int ks = 0; ks < 4; ++ks)
        a[ks] = *(const h8*)&X[(size_t)rowc * D + ks * 32 + lk * 8];
    }
    f4 acc[8];
#pragma unroll
    for (int ct = 0; ct < 8; ++ct) acc[ct] = (f4){0.f, 0.f, 0.f, 0.f};
#pragma unroll
    for (int ct = 0; ct < 8; ++ct) {
#pragma unroll
      for (int ks = 0; ks < 4; ++ks) {
        h8 b = *(const h8*)&Wl[(ct * 16 + lr) * 136 + ks * 32 + lk * 8];
        acc[ct] = __builtin_amdgcn_mfma_f32_16x16x32_f16(a[ks], b, acc[ct], 0, 0, 0);
      }
    }
#pragma unroll
    for (int r = 0; r < 4; ++r) {
      int ro = row0 + lk * 4 + r;
      if (ro < N) {
        float sc = nrm[ro];
#pragma unroll
        for (int ct = 0; ct < 8; ++ct)
          Hh[(size_t)ro * D + ct * 16 + lr] = (_Float16)(acc[ct][r] * sc);
      }
    }
  }
}

// ---- Fused aggregate + self-loop + bias + ReLU --------------------------
// One wave per node; 16-lane group reads a full 256B fp16 row (h8/lane);
// 4 chains x 4 groups = 16 edges (16 b128 loads) in flight.
#define ACC8(A, v)                                                        \
  {                                                                       \
    A[0] += (float)v[0]; A[1] += (float)v[1]; A[2] += (float)v[2];        \
    A[3] += (float)v[3]; A[4] += (float)v[4]; A[5] += (float)v[5];        \
    A[6] += (float)v[6]; A[7] += (float)v[7];                             \
  }

template <bool F16OUT>
__global__ __launch_bounds__(256) void agg_k(const _Float16* __restrict__ Hh,
                                             const float* __restrict__ nrm,
                                             const int* __restrict__ row_start,
                                             const int* __restrict__ esrc,
                                             const float* __restrict__ bias,
                                             void* __restrict__ outv, int N) {
  int wave = threadIdx.x >> 6, lane = threadIdx.x & 63;
  int n = blockIdx.x * 4 + wave;
  if (n >= N) return;
  int grp = lane >> 4, sub = lane & 15;
  int d0 = sub * 8;
  int i0 = row_start[n], end = row_start[n + 1];
  float a0[8] = {}, a1[8] = {}, a2[8] = {}, a3[8] = {};
  for (int i = i0; i < end; i += 16) {
    int e0 = i + grp, e1 = i + 4 + grp, e2 = i + 8 + grp, e3 = i + 12 + grp;
    if (e3 < end) {
      int s0 = esrc[e0], s1 = esrc[e1], s2 = esrc[e2], s3 = esrc[e3];
      h8 v0 = *(const h8*)&Hh[(size_t)s0 * D + d0];
      h8 v1 = *(const h8*)&Hh[(size_t)s1 * D + d0];
      h8 v2 = *(const h8*)&Hh[(size_t)s2 * D + d0];
      h8 v3 = *(const h8*)&Hh[(size_t)s3 * D + d0];
      ACC8(a0, v0); ACC8(a1, v1); ACC8(a2, v2); ACC8(a3, v3);
    } else {
      if (e0 < end) {
        int s0 = esrc[e0];
        h8 v0 = *(const h8*)&Hh[(size_t)s0 * D + d0];
        ACC8(a0, v0);
      }
      if (e1 < end) {
        int s1 = esrc[e1];
        h8 v1 = *(const h8*)&Hh[(size_t)s1 * D + d0];
        ACC8(a1, v1);
      }
      if (e2 < end) {
        int s2 = esrc[e2];
        h8 v2 = *(const h8*)&Hh[(size_t)s2 * D + d0];
        ACC8(a2, v2);
      }
    }
  }
  float r[8];
#pragma unroll
  for (int j = 0; j < 8; ++j) r[j] = (a0[j] + a1[j]) + (a2[j] + a3[j]);
#pragma unroll
  for (int j = 0; j < 8; ++j) r[j] += __shfl_xor(r[j], 16);
#pragma unroll
  for (int j = 0; j < 8; ++j) r[j] += __shfl_xor(r[j], 32);
  if (grp == 0) {
    h8 hv = *(const h8*)&Hh[(size_t)n * D + d0];
    float nn = nrm[n];
    f4 bl = *(const f4*)&bias[d0];
    f4 bh = *(const f4*)&bias[d0 + 4];
    float o[8];
#pragma unroll
    for (int j = 0; j < 8; ++j) {
      float bj = (j < 4) ? bl[j] : bh[j - 4];
      o[j] = fmaxf((r[j] + (float)hv[j]) * nn + bj, 0.f);
    }
    if constexpr (F16OUT) {
      _Float16* out = (_Float16*)outv;
      h8 ov;
#pragma unroll
      for (int j = 0; j < 8; ++j) ov[j] = (_Float16)o[j];
      *(h8*)&out[(size_t)n * D + d0] = ov;
    } else {
      float* out = (float*)outv;
      f4 lo = {o[0], o[1], o[2], o[3]};
      f4 hi = {o[4], o[5], o[6], o[7]};
      *(f4*)&out[(size_t)n * D + d0] = lo;
      *(f4*)&out[(size_t)n * D + d0 + 4] = hi;
    }
  }
}

// ---- launch -------------------------------------------------------------

extern "C" void kernel_launch(void* const* d_in, const int* in_sizes, int n_in,
                              void* d_out, int out_size, void* d_ws, size_t ws_size,
                              hipStream_t stream) {
  const float* x  = (const float*)d_in[0];
  const int*   ei = (const int*)d_in[1];
  const float* W1 = (const float*)d_in[2];
  const float* b1 = (const float*)d_in[3];
  const float* W2 = (const float*)d_in[4];
  const float* b2 = (const float*)d_in[5];
  float* out = (float*)d_out;

  int N = in_sizes[0] / D;   // 100000
  int E = in_sizes[1] / 2;   // 1600000
  const int* srcp = ei;
  const int* dstp = ei + E;

  int NB = (N + 255) / 256;        // 391 dst-buckets
  int G  = (E + EG - 1) / EG;      // 391 edge groups
  int M  = NB * G;
  int nbM = (M + 255) / 256;       // <= 1024 for bscan_k

  char* ws = (char*)d_ws;
  size_t off = 0;
  auto alloc = [&](size_t bytes) -> char* {
    char* p = ws + off;
    off = (off + bytes + 511) & ~(size_t)511;
    return p;
  };
  _Float16* Hh   = (_Float16*)alloc((size_t)N * D * 2);  // 25.6 MB
  _Float16* O1h  = (_Float16*)alloc((size_t)N * D * 2);  // 25.6 MB
  float* normv     = (float*)alloc((size_t)N * 4);
  int*   row_start = (int*)alloc((size_t)(N + 1) * 4);
  int*   counts    = (int*)alloc((size_t)M * 4);
  int*   cscan     = (int*)alloc((size_t)M * 4);
  unsigned* tmp    = (unsigned*)alloc((size_t)E * 4);
  int*   esrc      = (int*)alloc((size_t)E * 4);
  int*   bsum      = (int*)alloc(4096);
  _Float16* WT1    = (_Float16*)alloc((size_t)D * D * 2);
  _Float16* WT2    = (_Float16*)alloc((size_t)D * D * 2);

  int tiles = (N + 15) / 16;            // 6250
  int nbGemm = (tiles + 7) / 8;         // 782 (8 tiles per block)
  int nbAgg = (N + 3) / 4;

  // weight transpose/convert (independent of CSR build)
  wtrans_k<<<64, 256, 0, stream>>>(W1, WT1);
  wtrans_k<<<64, 256, 0, stream>>>(W2, WT2);

  // CSR build (no global atomics)
  hist_k<<<G, 256, 0, stream>>>(dstp, counts, E, NB, G);
  bsum_k<<<nbM, 256, 0, stream>>>(counts, bsum, M);
  bscan_k<<<1, 1024, 0, stream>>>(bsum, nbM);
  scanfin_k<<<nbM, 256, 0, stream>>>(counts, bsum, cscan, M);
  scatter_k<<<G, 256, 0, stream>>>(srcp, dstp, cscan, tmp, E, NB, G);
  bucket_k<<<NB, 256, 0, stream>>>(tmp, cscan, normv, row_start, esrc, N, E, NB, G);

  // Layer 1
  gemm_k<true><<<nbGemm, 256, 0, stream>>>(x, WT1, normv, Hh, N);
  agg_k<true><<<nbAgg, 256, 0, stream>>>(Hh, normv, row_start, esrc, b1, O1h, N);
  // Layer 2
  gemm_k<false><<<nbGemm, 256, 0, stream>>>(O1h, WT2, normv, Hh, N);
  agg_k<false><<<nbAgg, 256, 0, stream>>>(Hh, normv, row_start, esrc, b2, out, N);
}

// Round 6
// 220.881 us; speedup vs baseline: 2.5718x; 1.0520x over previous
//
#include <hip/hip_runtime.h>

#define D 128
#define EG 4096   // edges per hist/scatter block
#define PADW 8    // row padding multiple (branch-free agg inner loop)

typedef _Float16 h8 __attribute__((ext_vector_type(8)));
typedef _Float16 h2 __attribute__((ext_vector_type(2)));
typedef float f4 __attribute__((ext_vector_type(4)));
typedef unsigned u4 __attribute__((ext_vector_type(4)));

// ---- CSR build via two-level LDS counting sort (no global atomics) ------

__global__ __launch_bounds__(256) void hist_k(const int* __restrict__ dst,
                                              int* __restrict__ counts,
                                              int E, int NB, int G) {
  __shared__ int hist[512];
  int g = blockIdx.x, t = threadIdx.x;
  for (int b = t; b < NB; b += 256) hist[b] = 0;
  __syncthreads();
  int e0 = g * EG;
#pragma unroll
  for (int it = 0; it < EG / 256; ++it) {
    int e = e0 + it * 256 + t;
    if (e < E) atomicAdd(&hist[dst[e] >> 8], 1);
  }
  __syncthreads();
  for (int b = t; b < NB; b += 256) counts[b * G + g] = hist[b];
}

__global__ __launch_bounds__(256) void bsum_k(const int* __restrict__ in,
                                              int* __restrict__ bsum, int M) {
  __shared__ int s[256];
  int t = threadIdx.x, i = blockIdx.x * 256 + t;
  s[t] = (i < M) ? in[i] : 0;
  __syncthreads();
  for (int off = 128; off > 0; off >>= 1) {
    if (t < off) s[t] += s[t + off];
    __syncthreads();
  }
  if (t == 0) bsum[blockIdx.x] = s[0];
}

__global__ __launch_bounds__(1024) void bscan_k(int* bsum, int nb) {
  __shared__ int s[1024];
  int t = threadIdx.x;
  s[t] = (t < nb) ? bsum[t] : 0;
  __syncthreads();
  for (int off = 1; off < 1024; off <<= 1) {
    int v = (t >= off) ? s[t - off] : 0;
    __syncthreads();
    s[t] += v;
    __syncthreads();
  }
  if (t < nb) bsum[t] = s[t];
}

__global__ __launch_bounds__(256) void scanfin_k(const int* __restrict__ in,
                                                 const int* __restrict__ bsum_incl,
                                                 int* __restrict__ outx, int M) {
  __shared__ int s[256];
  int b = blockIdx.x, t = threadIdx.x, i = b * 256 + t;
  int v0 = (i < M) ? in[i] : 0;
  s[t] = v0;
  __syncthreads();
  for (int off = 1; off < 256; off <<= 1) {
    int v = (t >= off) ? s[t - off] : 0;
    __syncthreads();
    s[t] += v;
    __syncthreads();
  }
  int base = (b > 0) ? bsum_incl[b - 1] : 0;
  if (i < M) outx[i] = base + s[t] - v0;
}

__global__ __launch_bounds__(256) void scatter_k(const int* __restrict__ src,
                                                 const int* __restrict__ dst,
                                                 const int* __restrict__ cscan,
                                                 unsigned* __restrict__ tmp,
                                                 int E, int NB, int G) {
  __shared__ int hist[512];
  __shared__ int base[512];
  int g = blockIdx.x, t = threadIdx.x;
  for (int b = t; b < NB; b += 256) {
    hist[b] = 0;
    base[b] = cscan[b * G + g];
  }
  __syncthreads();
  int e0 = g * EG;
#pragma unroll
  for (int it = 0; it < EG / 256; ++it) {
    int e = e0 + it * 256 + t;
    if (e < E) {
      int d = dst[e];
      int b = d >> 8;
      int r = atomicAdd(&hist[b], 1);
      tmp[base[b] + r] = ((unsigned)(d & 255) << 20) | (unsigned)src[e];
    }
  }
}

// Phase 4: per-bucket count/scan/rank; rows PADDED to multiple of PADW with
// dummy byte-offset N*256 (zero row). eoff stores BYTE offsets (src*256).
__global__ __launch_bounds__(256) void bucket_k(const unsigned* __restrict__ tmp,
                                                const int* __restrict__ cscan,
                                                float* __restrict__ nrm,
                                                int2* __restrict__ rs2,
                                                int* __restrict__ eoff,
                                                int N, int E, int NB, int G) {
  __shared__ int cnt[256];
  __shared__ int sc[256];
  __shared__ int cur[256];
  int b = blockIdx.x, t = threadIdx.x;
  int seg0 = cscan[b * G];
  int seg1 = (b == NB - 1) ? E : cscan[(b + 1) * G];
  int pbase = seg0 + b * 256 * (PADW - 1);  // per-bucket padded base
  cnt[t] = 0;
  __syncthreads();
  for (int i = seg0 + t; i < seg1; i += 256)
    atomicAdd(&cnt[tmp[i] >> 20], 1);
  __syncthreads();
  int v0 = cnt[t];
  int pd = (v0 + PADW - 1) & ~(PADW - 1);
  sc[t] = pd;
  __syncthreads();
  for (int off = 1; off < 256; off <<= 1) {
    int v = (t >= off) ? sc[t - off] : 0;
    __syncthreads();
    sc[t] += v;
    __syncthreads();
  }
  int ex = sc[t] - pd;  // exclusive padded scan within bucket
  cur[t] = pbase + ex;
  int node = b * 256 + t;
  if (node < N) {
    rs2[node] = make_int2(pbase + ex, pbase + ex + pd);
    nrm[node] = rsqrtf((float)v0 + 1.0f);
  }
  // fill padding slots with dummy (zero-row) byte offset
  int dummy = N * 256;
  for (int k = v0; k < pd; ++k) eoff[pbase + ex + k] = dummy;
  __syncthreads();
  for (int i = seg0 + t; i < seg1; i += 256) {
    unsigned p = tmp[i];
    int r = atomicAdd(&cur[p >> 20], 1);
    eoff[r] = (int)((p & 0xFFFFF) << 8);  // src*256 byte offset
  }
}

// zero the dummy gather row Hh[N]
__global__ void zero_k(_Float16* __restrict__ Hh, int N) {
  int t = threadIdx.x;
  if (t < 128) Hh[(size_t)N * D + t] = (_Float16)0.f;
}

// ---- W transpose + fp16 convert: WT[col][k] = fp16(W[k][col]) -----------
__global__ __launch_bounds__(256) void wtrans_k(const float* __restrict__ W,
                                                _Float16* __restrict__ WT) {
  int idx = blockIdx.x * 256 + threadIdx.x;
  int k = idx >> 7, col = idx & 127;
  WT[col * D + k] = (_Float16)W[idx];
}

// ---- MFMA GEMM + norm fuse: Hh = fp16((X @ W) * nrm[row]) ---------------
template <bool FP32IN>
__global__ __launch_bounds__(256) void gemm_k(const void* __restrict__ Xv,
                                              const _Float16* __restrict__ WT,
                                              const float* __restrict__ nrm,
                                              _Float16* __restrict__ Hh, int N) {
  __shared__ _Float16 Wl[D * 136];
  int tid = threadIdx.x;
#pragma unroll
  for (int it = 0; it < 8; ++it) {
    int idx = it * 256 + tid;
    int col = idx >> 4, kseg = idx & 15;
    *(h8*)&Wl[col * 136 + kseg * 8] = *(const h8*)&WT[col * D + kseg * 8];
  }
  __syncthreads();
  int wave = tid >> 6, lane = tid & 63;
  int lr = lane & 15, lk = lane >> 4;
#pragma unroll
  for (int tt = 0; tt < 2; ++tt) {
    int tile = blockIdx.x * 8 + wave * 2 + tt;
    int row0 = tile * 16;
    if (row0 >= N) break;
    int row = row0 + lr;
    int rowc = row < N ? row : N - 1;
    h8 a[4];
    if constexpr (FP32IN) {
      const float* X = (const float*)Xv;
#pragma unroll
      for (int ks = 0; ks < 4; ++ks) {
        f4 p = *(const f4*)&X[(size_t)rowc * D + ks * 32 + lk * 8];
        f4 q = *(const f4*)&X[(size_t)rowc * D + ks * 32 + lk * 8 + 4];
        h8 t;
        t[0] = (_Float16)p[0]; t[1] = (_Float16)p[1];
        t[2] = (_Float16)p[2]; t[3] = (_Float16)p[3];
        t[4] = (_Float16)q[0]; t[5] = (_Float16)q[1];
        t[6] = (_Float16)q[2]; t[7] = (_Float16)q[3];
        a[ks] = t;
      }
    } else {
      const _Float16* X = (const _Float16*)Xv;
#pragma unroll
      for (int ks = 0; ks < 4; ++ks)
        a[ks] = *(const h8*)&X[(size_t)rowc * D + ks * 32 + lk * 8];
    }
    f4 acc[8];
#pragma unroll
    for (int ct = 0; ct < 8; ++ct) acc[ct] = (f4){0.f, 0.f, 0.f, 0.f};
#pragma unroll
    for (int ct = 0; ct < 8; ++ct) {
#pragma unroll
      for (int ks = 0; ks < 4; ++ks) {
        h8 b = *(const h8*)&Wl[(ct * 16 + lr) * 136 + ks * 32 + lk * 8];
        acc[ct] = __builtin_amdgcn_mfma_f32_16x16x32_f16(a[ks], b, acc[ct], 0, 0, 0);
      }
    }
#pragma unroll
    for (int r = 0; r < 4; ++r) {
      int ro = row0 + lk * 4 + r;
      if (ro < N) {
        float sc = nrm[ro];
#pragma unroll
        for (int ct = 0; ct < 8; ++ct)
          Hh[(size_t)ro * D + ct * 16 + lr] = (_Float16)(acc[ct][r] * sc);
      }
    }
  }
}

// ---- Fused aggregate + self-loop + bias + ReLU --------------------------
// One wave per node; 16-lane group reads one 256B fp16 row (h8/lane).
// Rows padded to PADW=8 -> branch-free; per 16-lane group, 2 edges/iter
// combined via v_perm pairing + v_dot2_f32_f16 (1 inst per 2 dims·2 edges).
template <bool F16OUT>
__global__ __launch_bounds__(256) void agg_k(const _Float16* __restrict__ Hh,
                                             const float* __restrict__ nrm,
                                             const int2* __restrict__ rs2,
                                             const int* __restrict__ eoff,
                                             const float* __restrict__ bias,
                                             void* __restrict__ outv, int N) {
  int wave = threadIdx.x >> 6, lane = threadIdx.x & 63;
  int n = blockIdx.x * 4 + wave;
  if (n >= N) return;
  int grp = lane >> 4, sub = lane & 15;
  unsigned soff = (unsigned)sub * 16u;  // byte offset of this lane's 8 dims
  int2 se = rs2[n];
  const char* base = (const char*)Hh;
  const h2 ones = {(_Float16)1.f, (_Float16)1.f};
  float acc[8] = {};
  for (int i = se.x; i < se.y; i += PADW) {
    int e0 = i + grp * 2;
    unsigned o0 = (unsigned)eoff[e0] + soff;
    unsigned o1 = (unsigned)eoff[e0 + 1] + soff;
    u4 v0 = *(const u4*)(base + o0);
    u4 v1 = *(const u4*)(base + o1);
#pragma unroll
    for (int k = 0; k < 4; ++k) {
      unsigned lo = __builtin_amdgcn_perm(v1[k], v0[k], 0x05040100u);
      unsigned hi = __builtin_amdgcn_perm(v1[k], v0[k], 0x07060302u);
      acc[2 * k] = __builtin_amdgcn_fdot2(__builtin_bit_cast(h2, lo), ones,
                                          acc[2 * k], false);
      acc[2 * k + 1] = __builtin_amdgcn_fdot2(__builtin_bit_cast(h2, hi), ones,
                                              acc[2 * k + 1], false);
    }
  }
#pragma unroll
  for (int j = 0; j < 8; ++j) acc[j] += __shfl_xor(acc[j], 16);
#pragma unroll
  for (int j = 0; j < 8; ++j) acc[j] += __shfl_xor(acc[j], 32);
  if (grp == 0) {
    int d0 = sub * 8;
    h8 hv = *(const h8*)&Hh[(size_t)n * D + d0];
    float nn = nrm[n];
    f4 bl = *(const f4*)&bias[d0];
    f4 bh = *(const f4*)&bias[d0 + 4];
    float o[8];
#pragma unroll
    for (int j = 0; j < 8; ++j) {
      float bj = (j < 4) ? bl[j] : bh[j - 4];
      o[j] = fmaxf((acc[j] + (float)hv[j]) * nn + bj, 0.f);
    }
    if constexpr (F16OUT) {
      _Float16* out = (_Float16*)outv;
      h8 ov;
#pragma unroll
      for (int j = 0; j < 8; ++j) ov[j] = (_Float16)o[j];
      *(h8*)&out[(size_t)n * D + d0] = ov;
    } else {
      float* out = (float*)outv;
      f4 lo = {o[0], o[1], o[2], o[3]};
      f4 hi = {o[4], o[5], o[6], o[7]};
      *(f4*)&out[(size_t)n * D + d0] = lo;
      *(f4*)&out[(size_t)n * D + d0 + 4] = hi;
    }
  }
}

// ---- launch -------------------------------------------------------------

extern "C" void kernel_launch(void* const* d_in, const int* in_sizes, int n_in,
                              void* d_out, int out_size, void* d_ws, size_t ws_size,
                              hipStream_t stream) {
  const float* x  = (const float*)d_in[0];
  const int*   ei = (const int*)d_in[1];
  const float* W1 = (const float*)d_in[2];
  const float* b1 = (const float*)d_in[3];
  const float* W2 = (const float*)d_in[4];
  const float* b2 = (const float*)d_in[5];
  float* out = (float*)d_out;

  int N = in_sizes[0] / D;   // 100000
  int E = in_sizes[1] / 2;   // 1600000
  const int* srcp = ei;
  const int* dstp = ei + E;

  int NB = (N + 255) / 256;        // 391 dst-buckets
  int G  = (E + EG - 1) / EG;      // 391 edge groups
  int M  = NB * G;
  int nbM = (M + 255) / 256;

  char* ws = (char*)d_ws;
  size_t off = 0;
  auto alloc = [&](size_t bytes) -> char* {
    char* p = ws + off;
    off = (off + bytes + 511) & ~(size_t)511;
    return p;
  };
  _Float16* Hh   = (_Float16*)alloc((size_t)(N + 1) * D * 2);  // +1 zero row
  _Float16* O1h  = (_Float16*)alloc((size_t)N * D * 2);
  float* normv     = (float*)alloc((size_t)N * 4);
  int2*  rs2       = (int2*)alloc((size_t)N * 8);
  int*   counts    = (int*)alloc((size_t)M * 4);
  int*   cscan     = (int*)alloc((size_t)M * 4);
  unsigned* tmp    = (unsigned*)alloc((size_t)E * 4);
  int*   eoff      = (int*)alloc((size_t)(E + NB * 256 * (PADW - 1)) * 4);
  int*   bsum      = (int*)alloc(4096);
  _Float16* WT1    = (_Float16*)alloc((size_t)D * D * 2);
  _Float16* WT2    = (_Float16*)alloc((size_t)D * D * 2);

  int tiles = (N + 15) / 16;
  int nbGemm = (tiles + 7) / 8;
  int nbAgg = (N + 3) / 4;

  // weight transpose/convert + zero dummy row (independent of CSR build)
  wtrans_k<<<64, 256, 0, stream>>>(W1, WT1);
  wtrans_k<<<64, 256, 0, stream>>>(W2, WT2);
  zero_k<<<1, 128, 0, stream>>>(Hh, N);

  // CSR build (no global atomics)
  hist_k<<<G, 256, 0, stream>>>(dstp, counts, E, NB, G);
  bsum_k<<<nbM, 256, 0, stream>>>(counts, bsum, M);
  bscan_k<<<1, 1024, 0, stream>>>(bsum, nbM);
  scanfin_k<<<nbM, 256, 0, stream>>>(counts, bsum, cscan, M);
  scatter_k<<<G, 256, 0, stream>>>(srcp, dstp, cscan, tmp, E, NB, G);
  bucket_k<<<NB, 256, 0, stream>>>(tmp, cscan, normv, rs2, eoff, N, E, NB, G);

  // Layer 1
  gemm_k<true><<<nbGemm, 256, 0, stream>>>(x, WT1, normv, Hh, N);
  agg_k<true><<<nbAgg, 256, 0, stream>>>(Hh, normv, rs2, eoff, b1, O1h, N);
  // Layer 2
  gemm_k<false><<<nbGemm, 256, 0, stream>>>(O1h, WT2, normv, Hh, N);
  agg_k<false><<<nbAgg, 256, 0, stream>>>(Hh, normv, rs2, eoff, b2, out, N);
}

// Round 7
// 215.729 us; speedup vs baseline: 2.6333x; 1.0239x over previous
//
#include <hip/hip_runtime.h>

#define D 128
#define EG 4096   // edges per hist/scatter block
#define PADW 16   // row padding multiple (branch-free agg, int4 offset loads)

typedef _Float16 h8 __attribute__((ext_vector_type(8)));
typedef _Float16 h2 __attribute__((ext_vector_type(2)));
typedef float f4 __attribute__((ext_vector_type(4)));
typedef unsigned u4 __attribute__((ext_vector_type(4)));

// ---- CSR build via two-level LDS counting sort (no global atomics) ------

__global__ __launch_bounds__(256) void hist_k(const int* __restrict__ dst,
                                              int* __restrict__ counts,
                                              int E, int NB, int G) {
  __shared__ int hist[512];
  int g = blockIdx.x, t = threadIdx.x;
  for (int b = t; b < NB; b += 256) hist[b] = 0;
  __syncthreads();
  int e0 = g * EG;
#pragma unroll
  for (int it = 0; it < EG / 256; ++it) {
    int e = e0 + it * 256 + t;
    if (e < E) atomicAdd(&hist[dst[e] >> 8], 1);
  }
  __syncthreads();
  for (int b = t; b < NB; b += 256) counts[b * G + g] = hist[b];
}

__global__ __launch_bounds__(256) void bsum_k(const int* __restrict__ in,
                                              int* __restrict__ bsum, int M) {
  __shared__ int s[256];
  int t = threadIdx.x, i = blockIdx.x * 256 + t;
  s[t] = (i < M) ? in[i] : 0;
  __syncthreads();
  for (int off = 128; off > 0; off >>= 1) {
    if (t < off) s[t] += s[t + off];
    __syncthreads();
  }
  if (t == 0) bsum[blockIdx.x] = s[0];
}

__global__ __launch_bounds__(1024) void bscan_k(int* bsum, int nb) {
  __shared__ int s[1024];
  int t = threadIdx.x;
  s[t] = (t < nb) ? bsum[t] : 0;
  __syncthreads();
  for (int off = 1; off < 1024; off <<= 1) {
    int v = (t >= off) ? s[t - off] : 0;
    __syncthreads();
    s[t] += v;
    __syncthreads();
  }
  if (t < nb) bsum[t] = s[t];
}

__global__ __launch_bounds__(256) void scanfin_k(const int* __restrict__ in,
                                                 const int* __restrict__ bsum_incl,
                                                 int* __restrict__ outx, int M) {
  __shared__ int s[256];
  int b = blockIdx.x, t = threadIdx.x, i = b * 256 + t;
  int v0 = (i < M) ? in[i] : 0;
  s[t] = v0;
  __syncthreads();
  for (int off = 1; off < 256; off <<= 1) {
    int v = (t >= off) ? s[t - off] : 0;
    __syncthreads();
    s[t] += v;
    __syncthreads();
  }
  int base = (b > 0) ? bsum_incl[b - 1] : 0;
  if (i < M) outx[i] = base + s[t] - v0;
}

__global__ __launch_bounds__(256) void scatter_k(const int* __restrict__ src,
                                                 const int* __restrict__ dst,
                                                 const int* __restrict__ cscan,
                                                 unsigned* __restrict__ tmp,
                                                 int E, int NB, int G) {
  __shared__ int hist[512];
  __shared__ int base[512];
  int g = blockIdx.x, t = threadIdx.x;
  for (int b = t; b < NB; b += 256) {
    hist[b] = 0;
    base[b] = cscan[b * G + g];
  }
  __syncthreads();
  int e0 = g * EG;
#pragma unroll
  for (int it = 0; it < EG / 256; ++it) {
    int e = e0 + it * 256 + t;
    if (e < E) {
      int d = dst[e];
      int b = d >> 8;
      int r = atomicAdd(&hist[b], 1);
      tmp[base[b] + r] = ((unsigned)(d & 255) << 20) | (unsigned)src[e];
    }
  }
}

// Phase 4: per-bucket count/scan/rank; rows PADDED to multiple of PADW with
// dummy byte-offset N*256 (zero row). eoff stores BYTE offsets (src*256).
// Padded arenas: bucket base aligned to 16 so int4 offset loads are aligned.
__global__ __launch_bounds__(256) void bucket_k(const unsigned* __restrict__ tmp,
                                                const int* __restrict__ cscan,
                                                float* __restrict__ nrm,
                                                int2* __restrict__ rs2,
                                                int* __restrict__ eoff,
                                                int N, int E, int NB, int G) {
  __shared__ int cnt[256];
  __shared__ int sc[256];
  __shared__ int cur[256];
  int b = blockIdx.x, t = threadIdx.x;
  int seg0 = cscan[b * G];
  int seg1 = (b == NB - 1) ? E : cscan[(b + 1) * G];
  int pbase = (seg0 + b * (256 * (PADW - 1) + 16) + 15) & ~15;
  cnt[t] = 0;
  __syncthreads();
  for (int i = seg0 + t; i < seg1; i += 256)
    atomicAdd(&cnt[tmp[i] >> 20], 1);
  __syncthreads();
  int v0 = cnt[t];
  int pd = (v0 + PADW - 1) & ~(PADW - 1);
  sc[t] = pd;
  __syncthreads();
  for (int off = 1; off < 256; off <<= 1) {
    int v = (t >= off) ? sc[t - off] : 0;
    __syncthreads();
    sc[t] += v;
    __syncthreads();
  }
  int ex = sc[t] - pd;  // exclusive padded scan within bucket
  cur[t] = pbase + ex;
  int node = b * 256 + t;
  if (node < N) {
    rs2[node] = make_int2(pbase + ex, pbase + ex + pd);
    nrm[node] = rsqrtf((float)v0 + 1.0f);
  }
  // fill padding slots with dummy (zero-row) byte offset
  int dummy = N * 256;
  for (int k = v0; k < pd; ++k) eoff[pbase + ex + k] = dummy;
  __syncthreads();
  for (int i = seg0 + t; i < seg1; i += 256) {
    unsigned p = tmp[i];
    int r = atomicAdd(&cur[p >> 20], 1);
    eoff[r] = (int)((p & 0xFFFFF) << 8);  // src*256 byte offset
  }
}

// zero the dummy gather row Hh[N]
__global__ void zero_k(_Float16* __restrict__ Hh, int N) {
  int t = threadIdx.x;
  if (t < 128) Hh[(size_t)N * D + t] = (_Float16)0.f;
}

// ---- W transpose + fp16 convert: WT[col][k] = fp16(W[k][col]) -----------
__global__ __launch_bounds__(256) void wtrans_k(const float* __restrict__ W,
                                                _Float16* __restrict__ WT) {
  int idx = blockIdx.x * 256 + threadIdx.x;
  int k = idx >> 7, col = idx & 127;
  WT[col * D + k] = (_Float16)W[idx];
}

// ---- MFMA GEMM + norm fuse: Hh = fp16((X @ W) * nrm[row]) ---------------
template <bool FP32IN>
__global__ __launch_bounds__(256) void gemm_k(const void* __restrict__ Xv,
                                              const _Float16* __restrict__ WT,
                                              const float* __restrict__ nrm,
                                              _Float16* __restrict__ Hh, int N) {
  __shared__ _Float16 Wl[D * 136];
  int tid = threadIdx.x;
#pragma unroll
  for (int it = 0; it < 8; ++it) {
    int idx = it * 256 + tid;
    int col = idx >> 4, kseg = idx & 15;
    *(h8*)&Wl[col * 136 + kseg * 8] = *(const h8*)&WT[col * D + kseg * 8];
  }
  __syncthreads();
  int wave = tid >> 6, lane = tid & 63;
  int lr = lane & 15, lk = lane >> 4;
#pragma unroll
  for (int tt = 0; tt < 2; ++tt) {
    int tile = blockIdx.x * 8 + wave * 2 + tt;
    int row0 = tile * 16;
    if (row0 >= N) break;
    int row = row0 + lr;
    int rowc = row < N ? row : N - 1;
    h8 a[4];
    if constexpr (FP32IN) {
      const float* X = (const float*)Xv;
#pragma unroll
      for (int ks = 0; ks < 4; ++ks) {
        f4 p = *(const f4*)&X[(size_t)rowc * D + ks * 32 + lk * 8];
        f4 q = *(const f4*)&X[(size_t)rowc * D + ks * 32 + lk * 8 + 4];
        h8 t;
        t[0] = (_Float16)p[0]; t[1] = (_Float16)p[1];
        t[2] = (_Float16)p[2]; t[3] = (_Float16)p[3];
        t[4] = (_Float16)q[0]; t[5] = (_Float16)q[1];
        t[6] = (_Float16)q[2]; t[7] = (_Float16)q[3];
        a[ks] = t;
      }
    } else {
      const _Float16* X = (const _Float16*)Xv;
#pragma unroll
      for (int ks = 0; ks < 4; ++ks)
        a[ks] = *(const h8*)&X[(size_t)rowc * D + ks * 32 + lk * 8];
    }
    f4 acc[8];
#pragma unroll
    for (int ct = 0; ct < 8; ++ct) acc[ct] = (f4){0.f, 0.f, 0.f, 0.f};
#pragma unroll
    for (int ct = 0; ct < 8; ++ct) {
#pragma unroll
      for (int ks = 0; ks < 4; ++ks) {
        h8 b = *(const h8*)&Wl[(ct * 16 + lr) * 136 + ks * 32 + lk * 8];
        acc[ct] = __builtin_amdgcn_mfma_f32_16x16x32_f16(a[ks], b, acc[ct], 0, 0, 0);
      }
    }
#pragma unroll
    for (int r = 0; r < 4; ++r) {
      int ro = row0 + lk * 4 + r;
      if (ro < N) {
        float sc = nrm[ro];
#pragma unroll
        for (int ct = 0; ct < 8; ++ct)
          Hh[(size_t)ro * D + ct * 16 + lr] = (_Float16)(acc[ct][r] * sc);
      }
    }
  }
}

// ---- Fused aggregate + self-loop + bias + ReLU --------------------------
// One wave per node; 16-lane group reads one 256B fp16 row (h8/lane).
// PADW=16: per group-iter one int4 offset load -> 4 independent gathers;
// next iteration's offsets prefetched before the VALU block.
template <bool F16OUT>
__global__ __launch_bounds__(256) void agg_k(const _Float16* __restrict__ Hh,
                                             const float* __restrict__ nrm,
                                             const int2* __restrict__ rs2,
                                             const int* __restrict__ eoff,
                                             const float* __restrict__ bias,
                                             void* __restrict__ outv, int N) {
  int wave = threadIdx.x >> 6, lane = threadIdx.x & 63;
  int n = blockIdx.x * 4 + wave;
  if (n >= N) return;
  int grp = lane >> 4, sub = lane & 15;
  unsigned soff = (unsigned)sub * 16u;
  int2 se = rs2[n];
  const char* base = (const char*)Hh;
  const h2 ones = {(_Float16)1.f, (_Float16)1.f};
  float acc[8] = {};
  int i = se.x;
  if (i < se.y) {
    u4 offs = *(const u4*)&eoff[i + grp * 4];
    while (true) {
      u4 v0 = *(const u4*)(base + offs[0] + soff);
      u4 v1 = *(const u4*)(base + offs[1] + soff);
      u4 v2 = *(const u4*)(base + offs[2] + soff);
      u4 v3 = *(const u4*)(base + offs[3] + soff);
      i += PADW;
      bool more = i < se.y;
      u4 offn;
      if (more) offn = *(const u4*)&eoff[i + grp * 4];  // prefetch next iter
#pragma unroll
      for (int k = 0; k < 4; ++k) {
        unsigned lo01 = __builtin_amdgcn_perm(v1[k], v0[k], 0x05040100u);
        unsigned hi01 = __builtin_amdgcn_perm(v1[k], v0[k], 0x07060302u);
        unsigned lo23 = __builtin_amdgcn_perm(v3[k], v2[k], 0x05040100u);
        unsigned hi23 = __builtin_amdgcn_perm(v3[k], v2[k], 0x07060302u);
        acc[2 * k] = __builtin_amdgcn_fdot2(__builtin_bit_cast(h2, lo01), ones,
                                            acc[2 * k], false);
        acc[2 * k + 1] = __builtin_amdgcn_fdot2(__builtin_bit_cast(h2, hi01), ones,
                                                acc[2 * k + 1], false);
        acc[2 * k] = __builtin_amdgcn_fdot2(__builtin_bit_cast(h2, lo23), ones,
                                            acc[2 * k], false);
        acc[2 * k + 1] = __builtin_amdgcn_fdot2(__builtin_bit_cast(h2, hi23), ones,
                                                acc[2 * k + 1], false);
      }
      if (!more) break;
      offs = offn;
    }
  }
#pragma unroll
  for (int j = 0; j < 8; ++j) acc[j] += __shfl_xor(acc[j], 16);
#pragma unroll
  for (int j = 0; j < 8; ++j) acc[j] += __shfl_xor(acc[j], 32);
  if (grp == 0) {
    int d0 = sub * 8;
    h8 hv = *(const h8*)&Hh[(size_t)n * D + d0];
    float nn = nrm[n];
    f4 bl = *(const f4*)&bias[d0];
    f4 bh = *(const f4*)&bias[d0 + 4];
    float o[8];
#pragma unroll
    for (int j = 0; j < 8; ++j) {
      float bj = (j < 4) ? bl[j] : bh[j - 4];
      o[j] = fmaxf((acc[j] + (float)hv[j]) * nn + bj, 0.f);
    }
    if constexpr (F16OUT) {
      _Float16* out = (_Float16*)outv;
      h8 ov;
#pragma unroll
      for (int j = 0; j < 8; ++j) ov[j] = (_Float16)o[j];
      *(h8*)&out[(size_t)n * D + d0] = ov;
    } else {
      float* out = (float*)outv;
      f4 lo = {o[0], o[1], o[2], o[3]};
      f4 hi = {o[4], o[5], o[6], o[7]};
      *(f4*)&out[(size_t)n * D + d0] = lo;
      *(f4*)&out[(size_t)n * D + d0 + 4] = hi;
    }
  }
}

// ---- launch -------------------------------------------------------------

extern "C" void kernel_launch(void* const* d_in, const int* in_sizes, int n_in,
                              void* d_out, int out_size, void* d_ws, size_t ws_size,
                              hipStream_t stream) {
  const float* x  = (const float*)d_in[0];
  const int*   ei = (const int*)d_in[1];
  const float* W1 = (const float*)d_in[2];
  const float* b1 = (const float*)d_in[3];
  const float* W2 = (const float*)d_in[4];
  const float* b2 = (const float*)d_in[5];
  float* out = (float*)d_out;

  int N = in_sizes[0] / D;   // 100000
  int E = in_sizes[1] / 2;   // 1600000
  const int* srcp = ei;
  const int* dstp = ei + E;

  int NB = (N + 255) / 256;        // 391 dst-buckets
  int G  = (E + EG - 1) / EG;      // 391 edge groups
  int M  = NB * G;
  int nbM = (M + 255) / 256;

  char* ws = (char*)d_ws;
  size_t off = 0;
  auto alloc = [&](size_t bytes) -> char* {
    char* p = ws + off;
    off = (off + bytes + 511) & ~(size_t)511;
    return p;
  };
  _Float16* Hh   = (_Float16*)alloc((size_t)(N + 1) * D * 2);  // +1 zero row
  _Float16* O1h  = (_Float16*)alloc((size_t)N * D * 2);
  float* normv     = (float*)alloc((size_t)N * 4);
  int2*  rs2       = (int2*)alloc((size_t)N * 8);
  int*   counts    = (int*)alloc((size_t)M * 4);
  int*   cscan     = (int*)alloc((size_t)M * 4);
  unsigned* tmp    = (unsigned*)alloc((size_t)E * 4);
  int*   eoff      = (int*)alloc((size_t)(E + (size_t)NB * (256 * (PADW - 1) + 16) + 16) * 4);
  int*   bsum      = (int*)alloc(4096);
  _Float16* WT1    = (_Float16*)alloc((size_t)D * D * 2);
  _Float16* WT2    = (_Float16*)alloc((size_t)D * D * 2);

  int tiles = (N + 15) / 16;
  int nbGemm = (tiles + 7) / 8;
  int nbAgg = (N + 3) / 4;

  // weight transpose/convert + zero dummy row (independent of CSR build)
  wtrans_k<<<64, 256, 0, stream>>>(W1, WT1);
  wtrans_k<<<64, 256, 0, stream>>>(W2, WT2);
  zero_k<<<1, 128, 0, stream>>>(Hh, N);

  // CSR build (no global atomics)
  hist_k<<<G, 256, 0, stream>>>(dstp, counts, E, NB, G);
  bsum_k<<<nbM, 256, 0, stream>>>(counts, bsum, M);
  bscan_k<<<1, 1024, 0, stream>>>(bsum, nbM);
  scanfin_k<<<nbM, 256, 0, stream>>>(counts, bsum, cscan, M);
  scatter_k<<<G, 256, 0, stream>>>(srcp, dstp, cscan, tmp, E, NB, G);
  bucket_k<<<NB, 256, 0, stream>>>(tmp, cscan, normv, rs2, eoff, N, E, NB, G);

  // Layer 1
  gemm_k<true><<<nbGemm, 256, 0, stream>>>(x, WT1, normv, Hh, N);
  agg_k<true><<<nbAgg, 256, 0, stream>>>(Hh, normv, rs2, eoff, b1, O1h, N);
  // Layer 2
  gemm_k<false><<<nbGemm, 256, 0, stream>>>(O1h, WT2, normv, Hh, N);
  agg_k<false><<<nbAgg, 256, 0, stream>>>(Hh, normv, rs2, eoff, b2, out, N);
}